// Round 1
// baseline (1638.947 us; speedup 1.0000x reference)
//
#include <hip/hip_runtime.h>
#include <math.h>

#define V 7
#define OPD 48
#define ND 48
#define HID 96
#define GD 128
#define NLAYER 5   // gcn0 + 4 shared-shape layers
#define NGATE 34   // 32 ops + input emb + output emb
#define NONE_OP 3
#define NB 8       // batch elements per block

// ---------------------------------------------------------------------------
// Precompute: gate tables (5 layers x 34 embeddings x 128 ch) and support0
// (7 x 128, batch-independent since node_embs don't depend on b).
// ---------------------------------------------------------------------------
__global__ void precompute_kernel(
    const float* __restrict__ op_tbl, const float* __restrict__ in_op,
    const float* __restrict__ out_op, const float* __restrict__ in_node,
    const float* __restrict__ other_node, const float* __restrict__ xh_W,
    const float* __restrict__ xh_b, const float* __restrict__ g0W,
    const float* __restrict__ g0attW, const float* __restrict__ g0attb,
    const float* __restrict__ gattW, const float* __restrict__ gattb,
    float* __restrict__ gates, float* __restrict__ sup0)
{
  const int blk = blockIdx.x;
  const int tid = threadIdx.x;  // 128 threads
  if (blk < NLAYER * NGATE) {
    const int l = blk / NGATE, e = blk % NGATE;
    const float* emb = (e < 32) ? (op_tbl + e * OPD) : (e == 32 ? in_op : out_op);
    const float* aW  = (l == 0) ? g0attW : (gattW + (size_t)(l - 1) * OPD * GD);
    const float* ab  = (l == 0) ? g0attb : (gattb + (l - 1) * GD);
    const int c = tid;
    float acc = ab[c];
    for (int j = 0; j < OPD; j++) acc += emb[j] * aW[j * GD + c];
    gates[(size_t)(l * NGATE + e) * GD + c] = 1.0f / (1.0f + expf(-acc));
  } else {
    __shared__ float x[V * HID];
    for (int i = tid; i < V * HID; i += blockDim.x) {
      const int v = i / HID, h = i % HID;
      const float* emb = (v == 0) ? in_node : other_node;
      float acc = xh_b[h];
      for (int j = 0; j < ND; j++) acc += emb[j] * xh_W[j * HID + h];
      x[i] = acc;
    }
    __syncthreads();
    for (int i = tid; i < V * GD; i += blockDim.x) {
      const int v = i / GD, c = i % GD;
      float acc = 0.f;
      for (int h = 0; h < HID; h++) acc += x[v * HID + h] * g0W[h * GD + c];
      sup0[i] = acc;
    }
  }
}

// ---------------------------------------------------------------------------
// Main fused kernel: 256 threads = 4 waves, 2 batch elements per wave.
// Lane owns channels (2*lane, 2*lane+1). y lives in LDS per (slot, node).
// ---------------------------------------------------------------------------
__global__ __launch_bounds__(256) void gin_main_kernel(
    const int* __restrict__ x_ops, const float* __restrict__ x_adj,
    const float* __restrict__ gates, const float* __restrict__ sup0,
    const float* __restrict__ g0_bias, const float* __restrict__ gcn_W,
    const float* __restrict__ gcn_bias,
    const float* __restrict__ m0W, const float* __restrict__ m0b,
    const float* __restrict__ m1W, const float* __restrict__ m1b,
    const float* __restrict__ m2W, const float* __restrict__ m2b,
    const float* __restrict__ m3W, const float* __restrict__ m3b,
    float* __restrict__ out)
{
  __shared__ float a_lds[NB][49];     // adj^T per slot
  __shared__ int   gi_lds[NB][V];     // gate index per node (v=0->32, v=6->33, else op)
  __shared__ float s0_lds[V * GD];    // support0
  __shared__ float z_lds[NB * GD];    // mean features (MLP input)
  __shared__ float y_lds[NB][V][GD];  // node features; reused as MLP act buffers
  float* act_a = &y_lds[0][0][0];     // NB*208 floats
  float* act_b = act_a + NB * 208;    // NB*208 floats (4352 total < 7168, fits)

  const int tid = threadIdx.x;
  const int bbase = blockIdx.x * NB;

  // ---- prologue: stage adj^T, gate indices, support0 ----
  for (int i = tid; i < NB * 49; i += 256) {
    const int s = i / 49, r = i % 49;
    const int v = r / 7, w = r % 7;
    a_lds[s][v * 7 + w] = x_adj[(size_t)(bbase + s) * 49 + w * 7 + v];  // transpose
  }
  for (int i = tid; i < NB * V; i += 256) {
    const int s = i / V, v = i % V;
    int g;
    if (v == 0) g = 32;
    else if (v == V - 1) g = 33;
    else g = x_ops[(size_t)(bbase + s) * V + v];
    gi_lds[s][v] = g;
  }
  for (int i = tid; i < V * GD; i += 256) s0_lds[i] = sup0[i];
  __syncthreads();

  const int lane = tid & 63;
  const int wave = tid >> 6;
  const int c0 = lane * 2;
  const int sl0 = wave * 2;

  // ---- layer 0: support is precomputed (same for all b) ----
  {
    float2 s0v[V];
#pragma unroll
    for (int v = 0; v < V; v++) s0v[v] = *(const float2*)&s0_lds[v * GD + c0];
    const float2 bias = *(const float2*)&g0_bias[c0];
    for (int bi = 0; bi < 2; bi++) {
      const int sl = sl0 + bi;
#pragma unroll
      for (int v = 0; v < V; v++) {
        float tx = 0.f, ty = 0.f;
#pragma unroll
        for (int w = 0; w < V; w++) {
          const float a = a_lds[sl][v * 7 + w];
          tx += a * s0v[w].x; ty += a * s0v[w].y;
        }
        const float2 g = *(const float2*)&gates[(size_t)(0 * NGATE + gi_lds[sl][v]) * GD + c0];
        const float rx = fmaxf(g.x * tx + s0v[v].x + bias.x, 0.f);
        const float ry = fmaxf(g.y * ty + s0v[v].y + bias.y, 0.f);
        y_lds[sl][v][c0]     = rx;
        y_lds[sl][v][c0 + 1] = ry;
      }
    }
  }
  __syncthreads();

  // ---- layers 1..4 ----
  float2 yn[2][V];  // last layer's outputs held in registers
  for (int l = 1; l <= 4; l++) {
    const float* Wl = gcn_W + (size_t)(l - 1) * GD * GD;
    const float2 bias = *(const float2*)&gcn_bias[(l - 1) * GD + c0];
    float2 sup[2][V];
#pragma unroll
    for (int bi = 0; bi < 2; bi++)
#pragma unroll
      for (int v = 0; v < V; v++) sup[bi][v] = make_float2(0.f, 0.f);

    // support = y @ W  (7x128 @ 128x128) for both slots of this wave
    for (int kb = 0; kb < GD / 4; kb++) {
      const int k = kb * 4;
      const float2 w0 = *(const float2*)&Wl[(size_t)(k + 0) * GD + c0];
      const float2 w1 = *(const float2*)&Wl[(size_t)(k + 1) * GD + c0];
      const float2 w2 = *(const float2*)&Wl[(size_t)(k + 2) * GD + c0];
      const float2 w3 = *(const float2*)&Wl[(size_t)(k + 3) * GD + c0];
#pragma unroll
      for (int bi = 0; bi < 2; bi++) {
        const int sl = sl0 + bi;
#pragma unroll
        for (int v = 0; v < V; v++) {
          const float4 y4 = *(const float4*)&y_lds[sl][v][k];  // broadcast read
          sup[bi][v].x += y4.x * w0.x + y4.y * w1.x + y4.z * w2.x + y4.w * w3.x;
          sup[bi][v].y += y4.x * w0.y + y4.y * w1.y + y4.z * w2.y + y4.w * w3.y;
        }
      }
    }

    // mix: y' = gate * (A @ support) + support + bias, relu except last layer
    for (int bi = 0; bi < 2; bi++) {
      const int sl = sl0 + bi;
#pragma unroll
      for (int v = 0; v < V; v++) {
        float tx = 0.f, ty = 0.f;
#pragma unroll
        for (int w = 0; w < V; w++) {
          const float a = a_lds[sl][v * 7 + w];
          tx += a * sup[bi][w].x; ty += a * sup[bi][w].y;
        }
        const float2 g = *(const float2*)&gates[(size_t)(l * NGATE + gi_lds[sl][v]) * GD + c0];
        float rx = g.x * tx + sup[bi][v].x + bias.x;
        float ry = g.y * ty + sup[bi][v].y + bias.y;
        if (l < 4) {
          rx = fmaxf(rx, 0.f); ry = fmaxf(ry, 0.f);
          y_lds[sl][v][c0]     = rx;
          y_lds[sl][v][c0 + 1] = ry;
        } else {
          yn[bi][v] = make_float2(rx, ry);
        }
      }
    }
    __syncthreads();
  }

  // ---- masked mean over nodes 1..6 (node 6 always kept) ----
  for (int bi = 0; bi < 2; bi++) {
    const int sl = sl0 + bi;
    float zx = yn[bi][6].x, zy = yn[bi][6].y;
#pragma unroll
    for (int v = 1; v <= 5; v++) {
      const float m = (gi_lds[sl][v] != NONE_OP) ? 1.f : 0.f;
      zx += m * yn[bi][v].x; zy += m * yn[bi][v].y;
    }
    z_lds[sl * GD + c0]     = zx * (1.f / 6.f);
    z_lds[sl * GD + c0 + 1] = zy * (1.f / 6.f);
  }
  __syncthreads();  // y_lds dead; act buffers may now alias it

  // ---- MLP: 128 -> 200 -> 200 -> 200 -> 1 ----
  for (int idx = tid; idx < NB * 200; idx += 256) {
    const int s = idx / 200, o = idx % 200;
    float acc = m0b[o];
    const float* z = &z_lds[s * GD];
    for (int k = 0; k < GD; k += 4) {
      const float4 z4 = *(const float4*)&z[k];
      acc += z4.x * m0W[(size_t)(k + 0) * 200 + o];
      acc += z4.y * m0W[(size_t)(k + 1) * 200 + o];
      acc += z4.z * m0W[(size_t)(k + 2) * 200 + o];
      acc += z4.w * m0W[(size_t)(k + 3) * 200 + o];
    }
    act_a[s * 208 + o] = fmaxf(acc, 0.f);
  }
  __syncthreads();
  for (int idx = tid; idx < NB * 200; idx += 256) {
    const int s = idx / 200, o = idx % 200;
    float acc = m1b[o];
    const float* a = &act_a[s * 208];
    for (int k = 0; k < 200; k += 4) {
      const float4 a4 = *(const float4*)&a[k];
      acc += a4.x * m1W[(size_t)(k + 0) * 200 + o];
      acc += a4.y * m1W[(size_t)(k + 1) * 200 + o];
      acc += a4.z * m1W[(size_t)(k + 2) * 200 + o];
      acc += a4.w * m1W[(size_t)(k + 3) * 200 + o];
    }
    act_b[s * 208 + o] = fmaxf(acc, 0.f);
  }
  __syncthreads();
  for (int idx = tid; idx < NB * 200; idx += 256) {
    const int s = idx / 200, o = idx % 200;
    float acc = m2b[o];
    const float* a = &act_b[s * 208];
    for (int k = 0; k < 200; k += 4) {
      const float4 a4 = *(const float4*)&a[k];
      acc += a4.x * m2W[(size_t)(k + 0) * 200 + o];
      acc += a4.y * m2W[(size_t)(k + 1) * 200 + o];
      acc += a4.z * m2W[(size_t)(k + 2) * 200 + o];
      acc += a4.w * m2W[(size_t)(k + 3) * 200 + o];
    }
    act_a[s * 208 + o] = fmaxf(acc, 0.f);
  }
  __syncthreads();
  {
    const int s = tid / 32, j = tid % 32;  // 8 slots x 32 lanes (exactly 256)
    float p = 0.f;
    for (int k = j; k < 200; k += 32) p += act_a[s * 208 + k] * m3W[k];
    for (int d = 16; d > 0; d >>= 1) p += __shfl_down(p, d, 32);
    if (j == 0) out[bbase + s] = p + m3b[0];
  }
}

// ---------------------------------------------------------------------------
extern "C" void kernel_launch(void* const* d_in, const int* in_sizes, int n_in,
                              void* d_out, int out_size, void* d_ws, size_t ws_size,
                              hipStream_t stream) {
  const int*   x_ops   = (const int*)  d_in[0];
  const float* x_adj   = (const float*)d_in[1];
  // d_in[2] = zcp (unused by the reference forward)
  const float* op_tbl  = (const float*)d_in[3];
  const float* in_op   = (const float*)d_in[4];
  const float* out_op  = (const float*)d_in[5];
  const float* in_node = (const float*)d_in[6];
  const float* oth_node= (const float*)d_in[7];
  const float* xh_W    = (const float*)d_in[8];
  const float* xh_b    = (const float*)d_in[9];
  const float* g0W     = (const float*)d_in[10];
  const float* g0attW  = (const float*)d_in[11];
  const float* g0attb  = (const float*)d_in[12];
  const float* g0bias  = (const float*)d_in[13];
  const float* gW      = (const float*)d_in[14];
  const float* gattW   = (const float*)d_in[15];
  const float* gattb   = (const float*)d_in[16];
  const float* gbias   = (const float*)d_in[17];
  const float* m0W = (const float*)d_in[18], *m0b = (const float*)d_in[19];
  const float* m1W = (const float*)d_in[20], *m1b = (const float*)d_in[21];
  const float* m2W = (const float*)d_in[22], *m2b = (const float*)d_in[23];
  const float* m3W = (const float*)d_in[24], *m3b = (const float*)d_in[25];
  float* out = (float*)d_out;

  float* gates = (float*)d_ws;                       // 5*34*128 floats
  float* sup0  = gates + NLAYER * NGATE * GD;        // 7*128 floats

  const int B = in_sizes[0] / V;

  hipLaunchKernelGGL(precompute_kernel, dim3(NLAYER * NGATE + 1), dim3(128), 0, stream,
                     op_tbl, in_op, out_op, in_node, oth_node, xh_W, xh_b,
                     g0W, g0attW, g0attb, gattW, gattb, gates, sup0);
  hipLaunchKernelGGL(gin_main_kernel, dim3(B / NB), dim3(256), 0, stream,
                     x_ops, x_adj, gates, sup0, g0bias, gW, gbias,
                     m0W, m0b, m1W, m1b, m2W, m2b, m3W, m3b, out);
}

// Round 3
// 504.176 us; speedup vs baseline: 3.2507x; 3.2507x over previous
//
#include <hip/hip_runtime.h>
#include <math.h>

#define V 7
#define OPD 48
#define HID 96
#define GD 128
#define NGATE 34
#define NONE_OP 3
#define NB 16

typedef unsigned short u16;
typedef unsigned int u32;
typedef _Float16 f16;
typedef __attribute__((ext_vector_type(8))) _Float16 f16x8;
typedef __attribute__((ext_vector_type(4))) float f32x4;

#define RSCALE 2048.0f
#define RINV   (1.0f/2048.0f)

// ---- workspace byte offsets ----
#define WS_GATES   0u        // [5][34][128] f32
#define WS_SUP0    87040u    // [7][128] f32
#define WS_GWH     90624u    // [4][128][128] f16  (Wt[n][k] hi)
#define WS_GWL     221696u   // lo * 2048
#define WS_W0H     352768u   // [208][128] f16
#define WS_W0L     406016u
#define WS_W1H     459264u   // [208][224] f16
#define WS_W1L     552448u
#define WS_W2H     645632u
#define WS_W2L     738816u

// ---- LDS byte offsets (dynamic, 76288 total -> 2 blocks/CU) ----
#define S_YH   0u        // [128][128] f16, sw256
#define S_YL   32768u
#define S_SUPT 0u        // ALIAS over Y: [128 cols][128 rows] f32, ssw
#define S_ADJ  65536u    // [16][7][8] f32
#define S_SUP0 69120u    // [128 cols][8] f32
#define S_BIAS 73216u    // [5][128] f32
#define S_GI   75776u    // [16][8] int
#define S_TOTAL 76288u
// post-GCN aliases inside the Y region:
#define S_ZH   0u        // [16][128] f16, sw256
#define S_ZL   4096u
#define S_A1H  8192u     // [16][256] f16, sw512
#define S_A1L  16384u
#define S_A2H  24576u
#define S_A2L  32768u

__device__ __forceinline__ u32 sw256(u32 row, u32 kb) { return row * 256u + (kb ^ ((row & 7u) << 4)); }
__device__ __forceinline__ u32 sw512(u32 row, u32 kb) { return row * 512u + (kb ^ ((row & 7u) << 4)); }
__device__ __forceinline__ u32 ssw(u32 col, u32 rb) { return col * 512u + (rb ^ (((col ^ (col >> 3)) & 7u) << 4)); }

#define MFMA(a, b, c) __builtin_amdgcn_mfma_f32_16x16x32_f16(a, b, c, 0, 0, 0)

// ===========================================================================
// Precompute: gate tables, support0, split/transposed f16 weights.
// ===========================================================================
__global__ __launch_bounds__(256) void precompute_kernel(
    const float* __restrict__ op_tbl, const float* __restrict__ in_op,
    const float* __restrict__ out_op, const float* __restrict__ in_node,
    const float* __restrict__ other_node, const float* __restrict__ xh_W,
    const float* __restrict__ xh_b, const float* __restrict__ g0W,
    const float* __restrict__ g0attW, const float* __restrict__ g0attb,
    const float* __restrict__ gattW, const float* __restrict__ gattb,
    const float* __restrict__ gW, const float* __restrict__ m0W,
    const float* __restrict__ m1W, const float* __restrict__ m2W,
    char* __restrict__ ws)
{
  const int blk = blockIdx.x, tid = threadIdx.x;
  float* gates = (float*)(ws + WS_GATES);
  float* sup0 = (float*)(ws + WS_SUP0);
  if (blk < 85) {                       // 170 gate rows, 2 per block
    const int row = blk * 2 + (tid >> 7);
    const int c = tid & 127;
    const int l = row / NGATE, e = row % NGATE;
    const float* emb = (e < 32) ? (op_tbl + e * OPD) : (e == 32 ? in_op : out_op);
    const float* aW = (l == 0) ? g0attW : (gattW + (size_t)(l - 1) * OPD * GD);
    const float* ab = (l == 0) ? g0attb : (gattb + (l - 1) * GD);
    float acc = ab[c];
    for (int j = 0; j < OPD; j++) acc += emb[j] * aW[j * GD + c];
    gates[(size_t)row * GD + c] = 1.0f / (1.0f + expf(-acc));
  } else if (blk == 85) {               // support0 (exact f32)
    __shared__ float x[V * HID];
    for (int i = tid; i < V * HID; i += 256) {
      const int v = i / HID, h = i % HID;
      const float* emb = (v == 0) ? in_node : other_node;
      float acc = xh_b[h];
      for (int j = 0; j < 48; j++) acc += emb[j] * xh_W[j * HID + h];
      x[i] = acc;
    }
    __syncthreads();
    for (int i = tid; i < V * GD; i += 256) {
      const int v = i / GD, c = i % GD;
      float acc = 0.f;
      for (int h = 0; h < HID; h++) acc += x[v * HID + h] * g0W[h * GD + c];
      sup0[i] = acc;
    }
  } else {                              // weight split+transpose (f16 hi/lo)
    for (int idx = (blk - 86) * 256 + tid; idx < 185344; idx += 128 * 256) {
      float w; f16 *ph, *pl;
      if (idx < 65536) {
        const int l = idx >> 14, rem = idx & 16383;
        const int n = rem >> 7, k = rem & 127;
        w = gW[(size_t)l * 16384 + k * 128 + n];
        ph = (f16*)(ws + WS_GWH) + idx; pl = (f16*)(ws + WS_GWL) + idx;
      } else if (idx < 92160) {
        const int j = idx - 65536, n = j >> 7, k = j & 127;
        w = (n < 200) ? m0W[(size_t)k * 200 + n] : 0.f;
        ph = (f16*)(ws + WS_W0H) + j; pl = (f16*)(ws + WS_W0L) + j;
      } else if (idx < 138752) {
        const int j = idx - 92160, n = j / 224, k = j % 224;
        w = (n < 200 && k < 200) ? m1W[(size_t)k * 200 + n] : 0.f;
        ph = (f16*)(ws + WS_W1H) + j; pl = (f16*)(ws + WS_W1L) + j;
      } else {
        const int j = idx - 138752, n = j / 224, k = j % 224;
        w = (n < 200 && k < 200) ? m2W[(size_t)k * 200 + n] : 0.f;
        ph = (f16*)(ws + WS_W2H) + j; pl = (f16*)(ws + WS_W2L) + j;
      }
      const f16 h = (f16)w;
      *ph = h;
      *pl = (f16)((w - (float)h) * RSCALE);
    }
  }
}

// ===========================================================================
// Main fused kernel. 256 threads, 16 slots/block, row = s*8 + v (M=128).
// ===========================================================================
__global__ __launch_bounds__(256, 2) void gin_main_kernel(
    const int* __restrict__ x_ops, const float* __restrict__ x_adj,
    const char* __restrict__ ws,
    const float* __restrict__ g0_bias, const float* __restrict__ gcn_bias,
    const float* __restrict__ m0b, const float* __restrict__ m1b,
    const float* __restrict__ m2b, const float* __restrict__ m3W,
    const float* __restrict__ m3b, float* __restrict__ out)
{
  extern __shared__ char smem[];
  const int tid = threadIdx.x;
  const int bbase = blockIdx.x * NB;
  const float* gates_ws = (const float*)(ws + WS_GATES);
  const float* sup0_ws = (const float*)(ws + WS_SUP0);
  const f16* GWH = (const f16*)(ws + WS_GWH);
  const f16* GWL = (const f16*)(ws + WS_GWL);
  const f16* W0H = (const f16*)(ws + WS_W0H);
  const f16* W0L = (const f16*)(ws + WS_W0L);
  const f16* W1H = (const f16*)(ws + WS_W1H);
  const f16* W1L = (const f16*)(ws + WS_W1L);
  const f16* W2H = (const f16*)(ws + WS_W2H);
  const f16* W2L = (const f16*)(ws + WS_W2L);

  // ---- prologue ----
  for (int i = tid; i < 16 * 56; i += 256) {
    const int s = i / 56, r = i % 56, v = r >> 3, w = r & 7;
    ((float*)(smem + S_ADJ))[i] = (w < 7) ? x_adj[(size_t)(bbase + s) * 49 + w * 7 + v] : 0.f;
  }
  if (tid < 128) {
    const int s = tid >> 3, v = tid & 7;
    const int g = (v == 0) ? 32 : (v == 6) ? 33 : (v == 7) ? 0
                : x_ops[(size_t)(bbase + s) * 7 + v];
    ((int*)(smem + S_GI))[tid] = g;
  }
  for (int i = tid; i < 1024; i += 256) {   // transposed sup0 [col][8]
    const int col = i >> 3, v = i & 7;
    ((float*)(smem + S_SUP0))[i] = (v < 7) ? sup0_ws[v * 128 + col] : 0.f;
  }
  for (int i = tid; i < 640; i += 256) {
    const int l = i >> 7, c = i & 127;
    ((float*)(smem + S_BIAS))[i] = (l == 0) ? g0_bias[c] : gcn_bias[(l - 1) * 128 + c];
  }
  __syncthreads();

  const int lane = tid & 63, wave = tid >> 6;
  const int lrow = lane & 15, lq = lane >> 4;
  const int ms = tid >> 4;            // mix: slot
  const int colbase = (tid & 15) * 8; // mix: col block

  // =================== GCN layers ===================
  for (int l = 0; l < 5; l++) {
    if (l > 0) {
      const f16* wh = GWH + (l - 1) * 16384;
      const f16* wl = GWL + (l - 1) * 16384;
      f32x4 acc0[8][2], acc1[8][2];
#pragma unroll
      for (int t = 0; t < 8; t++)
#pragma unroll
        for (int nt = 0; nt < 2; nt++) {
          acc0[t][nt] = (f32x4){0.f, 0.f, 0.f, 0.f};
          acc1[t][nt] = (f32x4){0.f, 0.f, 0.f, 0.f};
        }
#pragma unroll
      for (int ks = 0; ks < 4; ks++) {
        f16x8 bh[2], bl[2];
#pragma unroll
        for (int nt = 0; nt < 2; nt++) {
          const int eo = (wave * 32 + nt * 16 + lrow) * 128 + ks * 32 + lq * 8;
          bh[nt] = *(const f16x8*)(wh + eo);
          bl[nt] = *(const f16x8*)(wl + eo);
        }
#pragma unroll
        for (int t = 0; t < 8; t++) {
          const u32 off = sw256((u32)(t * 16 + lrow), (u32)(ks * 64 + lq * 16));
          const f16x8 ah = *(const f16x8*)(smem + S_YH + off);
          const f16x8 al = *(const f16x8*)(smem + S_YL + off);
#pragma unroll
          for (int nt = 0; nt < 2; nt++) {
            acc0[t][nt] = MFMA(ah, bh[nt], acc0[t][nt]);
            acc1[t][nt] = MFMA(ah, bl[nt], acc1[t][nt]);
            acc1[t][nt] = MFMA(al, bh[nt], acc1[t][nt]);
          }
        }
      }
      __syncthreads();   // all waves done reading Y; SUPT may now clobber it
#pragma unroll
      for (int t = 0; t < 8; t++)
#pragma unroll
        for (int nt = 0; nt < 2; nt++) {
          const u32 col = (u32)(wave * 32 + nt * 16 + lrow);
          f32x4 vv;
#pragma unroll
          for (int r = 0; r < 4; r++) vv[r] = acc0[t][nt][r] + acc1[t][nt][r] * RINV;
          *(f32x4*)(smem + S_SUPT + ssw(col, (u32)(t * 64 + lq * 16))) = vv;
        }
      __syncthreads();
    }

    // ---- phase C: load support for this thread's (slot, cols) into regs ----
    f32x4 sa[8], sb[8];
    if (l == 0) {
#pragma unroll
      for (int c = 0; c < 8; c++) {
        const u32 o = (u32)(colbase + c) * 32u;
        sa[c] = *(const f32x4*)(smem + S_SUP0 + o);
        sb[c] = *(const f32x4*)(smem + S_SUP0 + o + 16);
      }
    } else {
#pragma unroll
      for (int c = 0; c < 8; c++) {
        const u32 col = (u32)(colbase + c);
        sa[c] = *(const f32x4*)(smem + S_SUPT + ssw(col, (u32)(ms * 32)));
        sb[c] = *(const f32x4*)(smem + S_SUPT + ssw(col, (u32)(ms * 32 + 16)));
      }
      __syncthreads();   // SUPT loaded to regs; Y region may now be rewritten
    }

    // ---- phase D: adjmix + gate + residual + bias (+relu / +masked-mean) ----
    {
      const f32x4 bb0 = *(const f32x4*)(smem + S_BIAS + (l * 128 + colbase) * 4);
      const f32x4 bb1 = *(const f32x4*)(smem + S_BIAS + (l * 128 + colbase) * 4 + 16);
      const int* giv = (const int*)(smem + S_GI) + ms * 8;
      float zacc[8];
#pragma unroll
      for (int c = 0; c < 8; c++) zacc[c] = 0.f;
#pragma unroll
      for (int v = 0; v < 7; v++) {
        const f32x4 a0 = *(const f32x4*)(smem + S_ADJ + (ms * 56 + v * 8) * 4);
        const f32x4 a1 = *(const f32x4*)(smem + S_ADJ + (ms * 56 + v * 8) * 4 + 16);
        const int gidx = giv[v];
        const f32x4* gp = (const f32x4*)(gates_ws + ((size_t)l * NGATE + gidx) * 128 + colbase);
        const f32x4 g0 = gp[0], g1 = gp[1];
        float y[8];
#pragma unroll
        for (int c = 0; c < 8; c++) {
          const float t = a0[0] * sa[c][0] + a0[1] * sa[c][1] + a0[2] * sa[c][2] + a0[3] * sa[c][3]
                        + a1[0] * sb[c][0] + a1[1] * sb[c][1] + a1[2] * sb[c][2];
          const float sv = (v < 4) ? sa[c][v] : sb[c][v - 4];
          const float gg = (c < 4) ? g0[c] : g1[c - 4];
          const float bv = (c < 4) ? bb0[c] : bb1[c - 4];
          y[c] = gg * t + sv + bv;
        }
        if (l < 4) {
          union { f16x8 v8; f16 e[8]; } ph, pl;
#pragma unroll
          for (int c = 0; c < 8; c++) {
            const float r = fmaxf(y[c], 0.f);
            const f16 h = (f16)r;
            ph.e[c] = h;
            pl.e[c] = (f16)((r - (float)h) * RSCALE);
          }
          const u32 yo = sw256((u32)(ms * 8 + v), (u32)(colbase * 2));
          *(f16x8*)(smem + S_YH + yo) = ph.v8;
          *(f16x8*)(smem + S_YL + yo) = pl.v8;
        } else {
          if ((v == 6) || (v >= 1 && gidx != NONE_OP))
#pragma unroll
            for (int c = 0; c < 8; c++) zacc[c] += y[c];
        }
      }
      if (l == 4) {
        union { f16x8 v8; f16 e[8]; } ph, pl;
#pragma unroll
        for (int c = 0; c < 8; c++) {
          const float z = zacc[c] * (1.f / 6.f);
          const f16 h = (f16)z;
          ph.e[c] = h;
          pl.e[c] = (f16)((z - (float)h) * RSCALE);
        }
        const u32 zo = sw256((u32)ms, (u32)(colbase * 2));
        *(f16x8*)(smem + S_ZH + zo) = ph.v8;
        *(f16x8*)(smem + S_ZL + zo) = pl.v8;
        for (int i = tid; i < 8192; i += 256) ((u32*)(smem + S_A1H))[i] = 0u; // zero act region
      }
    }
    __syncthreads();
  }

  // =================== MLP ===================
  // L0: Z(16x128) @ W0t(208x128) -> A1
  {
    f32x4 macc0[4], macc1[4];
#pragma unroll
    for (int i = 0; i < 4; i++) { macc0[i] = (f32x4){0.f,0.f,0.f,0.f}; macc1[i] = (f32x4){0.f,0.f,0.f,0.f}; }
#pragma unroll
    for (int ks = 0; ks < 4; ks++) {
      const u32 off = sw256((u32)lrow, (u32)(ks * 64 + lq * 16));
      const f16x8 zh = *(const f16x8*)(smem + S_ZH + off);
      const f16x8 zl = *(const f16x8*)(smem + S_ZL + off);
#pragma unroll
      for (int i = 0; i < 4; i++) {
        const int nt = wave + i * 4;
        if (nt < 13) {
          const int eo = (nt * 16 + lrow) * 128 + ks * 32 + lq * 8;
          const f16x8 wh8 = *(const f16x8*)(W0H + eo);
          const f16x8 wl8 = *(const f16x8*)(W0L + eo);
          macc0[i] = MFMA(zh, wh8, macc0[i]);
          macc1[i] = MFMA(zh, wl8, macc1[i]);
          macc1[i] = MFMA(zl, wh8, macc1[i]);
        }
      }
    }
#pragma unroll
    for (int i = 0; i < 4; i++) {
      const int nt = wave + i * 4;
      if (nt < 13) {
        const int col = nt * 16 + lrow;
        const float b = (col < 200) ? m0b[col] : 0.f;
#pragma unroll
        for (int r = 0; r < 4; r++) {
          const float a = fmaxf(macc0[i][r] + macc1[i][r] * RINV + b, 0.f);
          const f16 h = (f16)a;
          const u32 off = sw512((u32)(lq * 4 + r), (u32)(2 * col));
          *(f16*)(smem + S_A1H + off) = h;
          *(f16*)(smem + S_A1L + off) = (f16)((a - (float)h) * RSCALE);
        }
      }
    }
  }
  __syncthreads();
  // L1: A1(16x224) @ W1t(208x224) -> A2
  {
    f32x4 macc0[4], macc1[4];
#pragma unroll
    for (int i = 0; i < 4; i++) { macc0[i] = (f32x4){0.f,0.f,0.f,0.f}; macc1[i] = (f32x4){0.f,0.f,0.f,0.f}; }
#pragma unroll
    for (int ks = 0; ks < 7; ks++) {
      const u32 off = sw512((u32)lrow, (u32)(ks * 64 + lq * 16));
      const f16x8 ah = *(const f16x8*)(smem + S_A1H + off);
      const f16x8 al = *(const f16x8*)(smem + S_A1L + off);
#pragma unroll
      for (int i = 0; i < 4; i++) {
        const int nt = wave + i * 4;
        if (nt < 13) {
          const int eo = (nt * 16 + lrow) * 224 + ks * 32 + lq * 8;
          const f16x8 wh8 = *(const f16x8*)(W1H + eo);
          const f16x8 wl8 = *(const f16x8*)(W1L + eo);
          macc0[i] = MFMA(ah, wh8, macc0[i]);
          macc1[i] = MFMA(ah, wl8, macc1[i]);
          macc1[i] = MFMA(al, wh8, macc1[i]);
        }
      }
    }
#pragma unroll
    for (int i = 0; i < 4; i++) {
      const int nt = wave + i * 4;
      if (nt < 13) {
        const int col = nt * 16 + lrow;
        const float b = (col < 200) ? m1b[col] : 0.f;
#pragma unroll
        for (int r = 0; r < 4; r++) {
          const float a = fmaxf(macc0[i][r] + macc1[i][r] * RINV + b, 0.f);
          const f16 h = (f16)a;
          const u32 off = sw512((u32)(lq * 4 + r), (u32)(2 * col));
          *(f16*)(smem + S_A2H + off) = h;
          *(f16*)(smem + S_A2L + off) = (f16)((a - (float)h) * RSCALE);
        }
      }
    }
  }
  __syncthreads();
  // L2: A2 @ W2t -> A3 (reuses A1 region; A1 dead)
  {
    f32x4 macc0[4], macc1[4];
#pragma unroll
    for (int i = 0; i < 4; i++) { macc0[i] = (f32x4){0.f,0.f,0.f,0.f}; macc1[i] = (f32x4){0.f,0.f,0.f,0.f}; }
#pragma unroll
    for (int ks = 0; ks < 7; ks++) {
      const u32 off = sw512((u32)lrow, (u32)(ks * 64 + lq * 16));
      const f16x8 ah = *(const f16x8*)(smem + S_A2H + off);
      const f16x8 al = *(const f16x8*)(smem + S_A2L + off);
#pragma unroll
      for (int i = 0; i < 4; i++) {
        const int nt = wave + i * 4;
        if (nt < 13) {
          const int eo = (nt * 16 + lrow) * 224 + ks * 32 + lq * 8;
          const f16x8 wh8 = *(const f16x8*)(W2H + eo);
          const f16x8 wl8 = *(const f16x8*)(W2L + eo);
          macc0[i] = MFMA(ah, wh8, macc0[i]);
          macc1[i] = MFMA(ah, wl8, macc1[i]);
          macc1[i] = MFMA(al, wh8, macc1[i]);
        }
      }
    }
#pragma unroll
    for (int i = 0; i < 4; i++) {
      const int nt = wave + i * 4;
      if (nt < 13) {
        const int col = nt * 16 + lrow;
        const float b = (col < 200) ? m2b[col] : 0.f;
#pragma unroll
        for (int r = 0; r < 4; r++) {
          const float a = fmaxf(macc0[i][r] + macc1[i][r] * RINV + b, 0.f);
          const f16 h = (f16)a;
          const u32 off = sw512((u32)(lq * 4 + r), (u32)(2 * col));
          *(f16*)(smem + S_A1H + off) = h;
          *(f16*)(smem + S_A1L + off) = (f16)((a - (float)h) * RSCALE);
        }
      }
    }
  }
  __syncthreads();
  // final: out[s] = A3[s] . m3W + b
  {
    const int kl = tid & 15;
    float p = 0.f;
    for (int k = kl; k < 200; k += 16) {
      const u32 off = sw512((u32)ms, (u32)(2 * k));
      const float a = (float)(*(const f16*)(smem + S_A1H + off))
                    + (float)(*(const f16*)(smem + S_A1L + off)) * RINV;
      p += a * m3W[k];
    }
#pragma unroll
    for (int d = 8; d > 0; d >>= 1) p += __shfl_down(p, d, 16);
    if (kl == 0) out[bbase + ms] = p + m3b[0];
  }
}

// ===========================================================================
extern "C" void kernel_launch(void* const* d_in, const int* in_sizes, int n_in,
                              void* d_out, int out_size, void* d_ws, size_t ws_size,
                              hipStream_t stream) {
  const int*   x_ops    = (const int*)  d_in[0];
  const float* x_adj    = (const float*)d_in[1];
  const float* op_tbl   = (const float*)d_in[3];
  const float* in_op    = (const float*)d_in[4];
  const float* out_op   = (const float*)d_in[5];
  const float* in_node  = (const float*)d_in[6];
  const float* oth_node = (const float*)d_in[7];
  const float* xh_W     = (const float*)d_in[8];
  const float* xh_b     = (const float*)d_in[9];
  const float* g0W      = (const float*)d_in[10];
  const float* g0attW   = (const float*)d_in[11];
  const float* g0attb   = (const float*)d_in[12];
  const float* g0bias   = (const float*)d_in[13];
  const float* gW       = (const float*)d_in[14];
  const float* gattW    = (const float*)d_in[15];
  const float* gattb    = (const float*)d_in[16];
  const float* gbias    = (const float*)d_in[17];
  const float* m0W = (const float*)d_in[18], *m0b = (const float*)d_in[19];
  const float* m1W = (const float*)d_in[20], *m1b = (const float*)d_in[21];
  const float* m2W = (const float*)d_in[22], *m2b = (const float*)d_in[23];
  const float* m3W = (const float*)d_in[24], *m3b = (const float*)d_in[25];
  float* out = (float*)d_out;
  char* ws = (char*)d_ws;
  (void)ws_size; (void)n_in; (void)out_size;

  const int B = in_sizes[0] / V;
  const int nblk = B / NB;

  hipFuncSetAttribute((const void*)gin_main_kernel,
                      hipFuncAttributeMaxDynamicSharedMemorySize, (int)S_TOTAL);

  hipLaunchKernelGGL(precompute_kernel, dim3(214), dim3(256), 0, stream,
                     op_tbl, in_op, out_op, in_node, oth_node, xh_W, xh_b,
                     g0W, g0attW, g0attb, gattW, gattb, gW, m0W, m1W, m2W, ws);
  hipLaunchKernelGGL(gin_main_kernel, dim3(nblk), dim3(256), (int)S_TOTAL, stream,
                     x_ops, x_adj, (const char*)ws, g0bias, gbias,
                     m0b, m1b, m2b, m3W, m3b, out);
}